// Round 18
// baseline (62.192 us; speedup 1.0000x reference)
//
#include <hip/hip_runtime.h>

// Problem constants
#define NDIM 471
#define MD   128
#define TD   16384
#define KSEL 50
#define CGIT 4

// ws float-offset layout
#define WS_PART   0                 // [256][471] column-sum partials
#define WS_G      120832            // [128][128] Gram
#define WS_T1     137216            // [128]  t1 = Q w
#define WS_XBAR   197888            // [471]
#define WS_W2     198400            // [471]
#define WS_RW     198912            // [471]  Rw = R @ w
#define WS_CTR    199384            // [1]    W2-done counter (zeroed by k2 each call)
#define WS_R      199424            // [471][471] R = (alpha/N) Q^T Ginv Q (row col = R[col][:], symmetric)

// SGPR broadcast: readlane with compile-time lane index -> v_readlane_b32 s,v,imm
static __device__ __forceinline__ float rdl(float v, int lane){
    return __int_as_float(__builtin_amdgcn_readlane(__float_as_int(v), lane));
}

// ---- Kernel 1 (grid 512 = 2 blocks/CU, no tail):
//      blocks 0..255 Gram; 256..511 colsum partials; 256..271 ALSO t1 slice ----
__global__ __launch_bounds__(512) void k_gram_colsum(const float* __restrict__ qt,
                                                     const float* __restrict__ x,
                                                     const float* __restrict__ wv,
                                                     float* __restrict__ ws){
    int lane = threadIdx.x & 63, wid = threadIdx.x >> 6;
    if (blockIdx.x < 256){
        float* G = ws + WS_G;
        int gw = blockIdx.x * 8 + wid;          // 0..2047 waves
        int i = gw >> 4, jb = gw & 15;
        float qi[8];
#pragma unroll
        for (int s = 0; s < 8; ++s){ int idx = lane + 64*s; qi[s] = (idx < NDIM) ? qt[i*NDIM + idx] : 0.f; }
#pragma unroll
        for (int t = 0; t < 8; ++t){
            int j = jb + 16*t;
            float acc = 0.f;
#pragma unroll
            for (int s = 0; s < 8; ++s){
                int idx = lane + 64*s;
                float qj = (idx < NDIM) ? qt[j*NDIM + idx] : 0.f;
                acc = fmaf(qi[s], qj, acc);
            }
#pragma unroll
            for (int d = 1; d < 64; d <<= 1) acc += __shfl_xor(acc, d);
            if (lane == 0) G[i*MD + j] = acc;
        }
    } else {
        int cb = blockIdx.x - 256;              // 0..255, rows cb*64..+64
        int col = threadIdx.x;
        if (col < NDIM){
            const float* xp = x + (size_t)cb*64*NDIM + col;
            float acc = 0.f;
#pragma unroll 4
            for (int r = 0; r < 64; ++r) acc += xp[(size_t)r*NDIM];
            ws[WS_PART + cb*NDIM + col] = acc;
        }
        if (cb < 16){
            int m = cb*8 + wid;                 // t1 slice: one row per wave
            float acc = 0.f;
#pragma unroll
            for (int s = 0; s < 8; ++s){
                int idx = lane + 64*s;
                if (idx < NDIM) acc = fmaf(qt[m*NDIM + idx], wv[idx], acc);
            }
#pragma unroll
            for (int d = 1; d < 64; d <<= 1) acc += __shfl_xor(acc, d);
            if (lane == 0) ws[WS_T1 + m] = acc;
        }
    }
}

// ---- Kernel 2 (grid 236 = 1 block/CU): CG (2 cols, 2 barriers/iter) + fused R/RW;
//      blocks 0..58 ALSO xbar finalize; block 130 zeroes the W2-done counter ----
#define G_LD(n) float4 t##n = *(const float4*)(Gp + 4*(n)); \
                float Ga##n = t##n.x, Gb##n = t##n.y, Gc##n = t##n.z, Gd##n = t##n.w;
#define G_DOT(n) pa = fmaf(Ga##n, rdl(rch.x, 2*(n)),   pa); \
                 pb = fmaf(Gb##n, rdl(rch.y, 2*(n)),   pb); \
                 pa = fmaf(Gc##n, rdl(rch.x, 2*(n)+1), pa); \
                 pb = fmaf(Gd##n, rdl(rch.y, 2*(n)+1), pb);

__global__ __launch_bounds__(256, 1) void k_cg_xbar(const float* __restrict__ qt,
                                                    const float* __restrict__ alpha,
                                                    float* __restrict__ ws){
    int tid = threadIdx.x, lane = tid & 63, wid = tid >> 6;
    if (blockIdx.x == 130 && tid == 0)
        __hip_atomic_store((unsigned*)(ws + WS_CTR), 0u, __ATOMIC_RELEASE, __HIP_MEMORY_SCOPE_AGENT);
    __shared__ __align__(16) float rl[2][2][128];    // [buf][c][row] — double-buffered r
    __shared__ float part[2][2][128];                // [seg][c][row] partial dots
    {
        int row = tid & 127, seg = tid >> 7;             // seg in {0,1}
        int c   = seg;
        int col = blockIdx.x*2 + c;                      // 0..471 (col 471 = t1 RHS)
        const float* Gp = ws + WS_G + row*MD + seg*64;   // 64 named scalars (true VGPRs)
        G_LD(0) G_LD(1) G_LD(2)  G_LD(3)  G_LD(4)  G_LD(5)  G_LD(6)  G_LD(7)
        G_LD(8) G_LD(9) G_LD(10) G_LD(11) G_LD(12) G_LD(13) G_LD(14) G_LD(15)
        float bvv = (col < NDIM) ? qt[row*NDIM + col] : ws[WS_T1 + row];
        float xv = 0.f, rv = bvv, pv = 0.f, sv = 0.f, gam = 1.f, alf = 1.f;
        int buf = 0;
        rl[0][c][row] = rv;
        for (int it = 0; it < CGIT; ++it){
            __syncthreads();                             // A: rl[buf] visible; part free
#pragma unroll
            for (int cc = 0; cc < 2; ++cc){
                float2 rch = *(const float2*)&rl[buf][cc][seg*64 + 2*(lane & 31)];
                float pa = 0.f, pb = 0.f;
                G_DOT(0) G_DOT(1) G_DOT(2)  G_DOT(3)  G_DOT(4)  G_DOT(5)  G_DOT(6)  G_DOT(7)
                G_DOT(8) G_DOT(9) G_DOT(10) G_DOT(11) G_DOT(12) G_DOT(13) G_DOT(14) G_DOT(15)
                part[seg][cc][row] = pa + pb;
            }
            __syncthreads();                             // B: part visible; rl[buf] reads done
            float y = part[0][c][row] + part[1][c][row];
            // dots redundant per wave (no 3rd barrier): rows lane & lane+64 of col c
            float r0 = rl[buf][c][lane],      r1 = rl[buf][c][lane + 64];
            float y0 = part[0][c][lane]      + part[1][c][lane];
            float y1 = part[0][c][lane + 64] + part[1][c][lane + 64];
            float t0 = fmaf(r0, r0, r1*r1);
            float t1 = fmaf(y0, r0, y1*r1);
#pragma unroll
            for (int d = 1; d < 64; d <<= 1){ t0 += __shfl_xor(t0, d); t1 += __shfl_xor(t1, d); }
            float gp = t0, dl = t1;                      // gamma'=(r,r), delta=(Gr,r)
            float bet, anew;
            if (it == 0){ bet = 0.f; anew = gp / fmaxf(dl, 1e-30f); }
            else { bet = gp / fmaxf(gam, 1e-30f); anew = gp / fmaxf(dl - bet*gp/alf, 1e-30f); }
            pv = fmaf(bet, pv, rv);
            sv = fmaf(bet, sv, y);
            xv = fmaf(anew, pv, xv);
            rv = fmaf(-anew, sv, rv);
            gam = gp; alf = anew;
            rl[buf^1][c][row] = rv;                      // write other buffer: no WAR race
            buf ^= 1;
        }
        // ---- fused epilogue: R rows 2b,2b+1 (or RW for col 471) ----
        rl[buf][c][row] = xv;                            // own slot; readers are on rl[buf^1]
        __syncthreads();
        float sc = alpha[0] / (float)NDIM;
        float2 wc0 = ((const float2*)&rl[buf][0][0])[lane];
        float2 wc1 = ((const float2*)&rl[buf][1][0])[lane];
        int i0 = tid;
        int i1 = (tid + 256 < NDIM) ? tid + 256 : (NDIM - 1);   // clamp (guarded store)
        float a0=0.f, a1=0.f, b0=0.f, b1=0.f;
#pragma unroll
        for (int l = 0; l < 64; ++l){
            float w0a = rdl(wc0.x, l), w0b = rdl(wc0.y, l);
            float w1a = rdl(wc1.x, l), w1b = rdl(wc1.y, l);
            float qa0 = qt[(2*l+0)*NDIM + i0], qa1 = qt[(2*l+0)*NDIM + i1];
            float qb0 = qt[(2*l+1)*NDIM + i0], qb1 = qt[(2*l+1)*NDIM + i1];
            a0 = fmaf(qa0, w0a, a0); a0 = fmaf(qb0, w0b, a0);
            a1 = fmaf(qa1, w0a, a1); a1 = fmaf(qb1, w0b, a1);
            b0 = fmaf(qa0, w1a, b0); b0 = fmaf(qb0, w1b, b0);
            b1 = fmaf(qa1, w1a, b1); b1 = fmaf(qb1, w1b, b1);
        }
        int col0 = blockIdx.x*2, col1 = col0 + 1;
        ws[WS_R + (size_t)col0*NDIM + i0] = sc*a0;
        if (tid + 256 < NDIM) ws[WS_R + (size_t)col0*NDIM + tid+256] = sc*a1;
        if (col1 < NDIM){
            ws[WS_R + (size_t)col1*NDIM + i0] = sc*b0;
            if (tid + 256 < NDIM) ws[WS_R + (size_t)col1*NDIM + tid+256] = sc*b1;
        } else {
            ws[WS_RW + i0] = sc*b0;
            if (tid + 256 < NDIM) ws[WS_RW + tid+256] = sc*b1;
        }
    }
    // ---- xbar finalize tail on blocks 0..58 ----
    if (blockIdx.x < 59){
        __shared__ float p2[4][8];
        __syncthreads();                        // retire epilogue LDS use before reuse
        int b2 = blockIdx.x;
        int cl = tid & 7, seg2 = tid >> 3;      // seg2 0..31
        int col = b2*8 + cl;
        float acc = 0.f;
        if (col < NDIM){
#pragma unroll
            for (int q = 0; q < 8; ++q) acc += ws[WS_PART + (seg2*8 + q)*NDIM + col];
        }
        acc += __shfl_xor(acc, 8);
        acc += __shfl_xor(acc, 16);
        acc += __shfl_xor(acc, 32);
        if (lane < 8) p2[wid][lane] = acc;
        __syncthreads();
        if (tid < 8){
            float t = ((p2[0][tid] + p2[1][tid]) + (p2[2][tid] + p2[3][tid]));
            int c2 = b2*8 + tid;
            if (c2 < NDIM) ws[WS_XBAR + c2] = t * (1.0f / TD);
        }
    }
}

// ---- Kernel 3: blocks 0..7 = W2 (59 rows each; only 8 releases -> ~1us atomic cost,
//      R16 lesson: contended agent-scope RMW ~100-200ns each, serialized);
//      block 8 = 10-iteration solver ----
__global__ __launch_bounds__(512, 2) void k_w2_iter(const float* __restrict__ lw, const float* __restrict__ lb,
                                              const float* __restrict__ wv,
                                              const float* __restrict__ alpha, const float* __restrict__ lamda,
                                              const float* __restrict__ rho_p, const float* __restrict__ mu_p,
                                              float* __restrict__ ws, float* __restrict__ out){
    int tid = threadIdx.x, lane = tid & 63, wid = tid >> 6;
    unsigned* ctr = (unsigned*)(ws + WS_CTR);

    if (blockIdx.x < 8){
        // ---- W2 rows [b*59, b*59+59): wave-per-row round robin, coalesced lw ----
        int base = blockIdx.x*59;
        int nrows = (base + 59 <= NDIM) ? 59 : (NDIM - base);
        for (int r = wid; r < nrows; r += 8){
            int i = base + r;
            float acc = 0.f;
#pragma unroll
            for (int s = 0; s < 8; ++s){
                int idx = lane + 64*s;
                if (idx < NDIM) acc = fmaf(lw[(size_t)i*NDIM + idx], ws[WS_XBAR + idx], acc);
            }
#pragma unroll
            for (int d = 1; d < 64; d <<= 1) acc += __shfl_xor(acc, d);
            if (lane == 0) ws[WS_W2 + i] = acc + lb[i];
        }
        __syncthreads();
        if (tid == 0)   // RELEASE add publishes prior stores
            __hip_atomic_fetch_add(ctr, 1u, __ATOMIC_RELEASE, __HIP_MEMORY_SCOPE_AGENT);
        return;
    }

    // ---- solver block ----
    bool act = tid < NDIM;
    int ti = act ? tid : 0;
    float rho = rho_p[0], mu = mu_p[0], lam = lamda[0];
    float sc  = alpha[0] / (float)NDIM;
    float wi  = act ? wv[tid]         : 0.f;
    float Rwi = act ? ws[WS_RW + tid] : 0.f;

    __shared__ __align__(16) unsigned bins[1024];   // 4 buffers x 256 bins
    __shared__ __align__(8) float2 spair[64];
    __shared__ float warr[8];
    __shared__ unsigned wcnt[8];

    bins[tid] = 0u; bins[tid + 512] = 0u;
    // RELAXED poll + one acquire fence (R15: ACQUIRE-in-loop = L2-invalidate storm)
    if (tid == 0){
        while (__hip_atomic_load(ctr, __ATOMIC_RELAXED, __HIP_MEMORY_SCOPE_AGENT) < 8u)
            __builtin_amdgcn_s_sleep(8);
        __builtin_amdgcn_fence(__ATOMIC_ACQUIRE, "agent");
    }
    __syncthreads();
    float W2i = act ? ws[WS_W2 + tid] : 0.f;

    float z = 0.f, u = 0.f, Ruv = 0.f, Rzv = 0.f, Sz = 0.f;
    unsigned tau = 0xFFFFFFFFu;                     // warm-start threshold (iter 0: forces full select)
    for (int it = 0; it < 10; ++it){
        float Rv = Ruv - rho*(Rzv - Rwi);
        float b  = wi + Rv;
        float grad = W2i + rho*(z - b) + u + 2.f*lam*(Sz - 1.f);
        float zn = z - mu*grad;
        zn = (act && zn > 0.f) ? zn : 0.f;
        unsigned bits = __float_as_uint(zn);

        // ---- warm-tau fast path: if exactly KSEL values >= tau_prev, that IS the top-50 ----
        bool cge = act && (bits >= tau);
        unsigned long long cm = __ballot(cge);
        if (lane == 0) wcnt[wid] = (unsigned)__popcll(cm);
        __syncthreads();
        int cnt0 = 0;
#pragma unroll
        for (int w2 = 0; w2 < 8; ++w2) cnt0 += (int)wcnt[w2];
        bool fast = (cnt0 == KSEL);
        unsigned prefix = tau;

        if (!fast){
            // full radix select with early exit (bins are pre-zeroed)
            prefix = 0; unsigned need = KSEL;
#pragma unroll
            for (int pass = 3; pass >= 0; --pass){
                int sh = pass*8;
                unsigned* bp = bins + ((3 - pass) << 8);
                bool av = (pass == 3) || ((bits >> (sh + 8)) == (prefix >> (sh + 8)));
                if (av) atomicAdd(&bp[(bits >> sh) & 255u], 1u);
                __syncthreads();
                int base = 255 - 4*lane;
                uint4 bq = *(const uint4*)&bp[base - 3];
                unsigned b3 = bq.x, b2 = bq.y, b1 = bq.z, b0 = bq.w;
                unsigned csum = b0 + b1 + b2 + b3;
                unsigned incl = csum;
#pragma unroll
                for (int d = 1; d < 64; d <<= 1){ unsigned t = __shfl_up(incl, d); if (lane >= d) incl += t; }
                unsigned excl = incl - csum;
                bool hit = (excl < need) && (need <= incl);
                unsigned long long hm = __ballot(hit);
                int hl = __ffsll((long long)hm) - 1;
                unsigned c0 = excl + b0, c1 = c0 + b1, c2 = c1 + b2;
                int byte; unsigned above, cntc;
                if      (need <= c0){ byte = base;   above = excl; cntc = b0; }
                else if (need <= c1){ byte = base-1; above = c0;   cntc = b1; }
                else if (need <= c2){ byte = base-2; above = c1;   cntc = b2; }
                else                { byte = base-3; above = c2;   cntc = b3; }
                byte  = __shfl(byte, hl);
                above = (unsigned)__shfl((int)above, hl);
                cntc  = (unsigned)__shfl((int)cntc, hl);
                prefix |= ((unsigned)byte) << sh;
                need -= above;
                if (cntc == need) break;
            }
            tau = prefix;
        }
        z = (act && bits >= prefix) ? zn : 0.f;

        // Sz + support list (fast path reuses cm/wcnt; miss path re-ballots)
        bool flag = z > 0.f;
        unsigned long long mb = fast ? cm : __ballot(flag);
        float v = z;
#pragma unroll
        for (int d = 1; d < 64; d <<= 1) v += __shfl_xor(v, d);
        if (lane == 0){ warr[wid] = v; if (!fast) wcnt[wid] = (unsigned)__popcll(mb); }
        __syncthreads();
        Sz = ((warr[0]+warr[1])+(warr[2]+warr[3])) + ((warr[4]+warr[5])+(warr[6]+warr[7]));

        if (it < 9){
            unsigned off = 0;
#pragma unroll
            for (int w2 = 0; w2 < 8; ++w2) if (w2 < wid) off += wcnt[w2];
            off += (unsigned)__popcll(mb & ((1ull << lane) - 1ull));
            int cnt = 0;
#pragma unroll
            for (int w2 = 0; w2 < 8; ++w2) cnt += (int)wcnt[w2];
            if (flag){ spair[off] = make_float2(__int_as_float(tid), z); }
            if (tid >= cnt && tid < 64){ spair[tid] = make_float2(__int_as_float(0), 0.f); }
            bins[tid] = 0u; bins[tid + 512] = 0u;
            __syncthreads();

            float2 pp = spair[lane];
            const float* Rb = ws + WS_R;
            float rvv[56];
#pragma unroll
            for (int s = 0; s < 56; ++s){
                int j = __float_as_int(rdl(pp.x, s));
                rvv[s] = Rb[(size_t)j*NDIM + ti];
            }
            float a0=0.f, a1=0.f, a2=0.f, a3=0.f;
#pragma unroll
            for (int s = 0; s < 56; s += 4){
                a0 = fmaf(rvv[s+0], rdl(pp.y, s+0), a0);
                a1 = fmaf(rvv[s+1], rdl(pp.y, s+1), a1);
                a2 = fmaf(rvv[s+2], rdl(pp.y, s+2), a2);
                a3 = fmaf(rvv[s+3], rdl(pp.y, s+3), a3);
            }
            float acc = (a0+a1) + (a2+a3);
            float Rbv = Rwi + sc*Rv;                // R@b = Rw + (alpha/N)*Rv   (P^2 = P)
            u   += rho*(z - b);
            Ruv += rho*(acc - Rbv);
            Rzv  = acc;
        }
    }
    if (act) out[tid] = z / (Sz + 1e-8f);
}

extern "C" void kernel_launch(void* const* d_in, const int* in_sizes, int n_in,
                              void* d_out, int out_size, void* d_ws, size_t ws_size,
                              hipStream_t stream) {
    const float* x     = (const float*)d_in[0];
    const float* qt    = (const float*)d_in[1];
    const float* wv    = (const float*)d_in[2];
    // d_in[3] = b1 (unused by forward math)
    const float* alpha = (const float*)d_in[4];
    const float* lamda = (const float*)d_in[5];
    const float* rho   = (const float*)d_in[6];
    const float* mu    = (const float*)d_in[7];
    const float* lw    = (const float*)d_in[8];
    const float* lb    = (const float*)d_in[9];
    float* out = (float*)d_out;
    float* ws  = (float*)d_ws;

    k_gram_colsum<<<512, 512, 0, stream>>>(qt, x, wv, ws);
    k_cg_xbar    <<<236, 256, 0, stream>>>(qt, alpha, ws);
    k_w2_iter    <<<9,   512, 0, stream>>>(lw, lb, wv, alpha, lamda, rho, mu, ws, out);
}

// Round 19
// 54.877 us; speedup vs baseline: 1.1333x; 1.1333x over previous
//
#include <hip/hip_runtime.h>

// Problem constants
#define NDIM 471
#define MD   128
#define TD   16384
#define KSEL 50
#define CGIT 4

// ws float-offset layout
#define WS_PART   0                 // [256][471] column-sum partials
#define WS_G      120832            // [128][128] Gram
#define WS_T1     137216            // [128]  t1 = Q w
#define WS_XBAR   197888            // [471]
#define WS_W2     198400            // [471]
#define WS_RW     198912            // [471]  Rw = R @ w
#define WS_CTR    199384            // [1]    xbar-done counter (zeroed by k1 each call)
#define WS_R      199424            // [471][471] R = (alpha/N) Q^T Ginv Q (row col = R[col][:], symmetric)

// SGPR broadcast: readlane with compile-time lane index -> v_readlane_b32 s,v,imm
static __device__ __forceinline__ float rdl(float v, int lane){
    return __int_as_float(__builtin_amdgcn_readlane(__float_as_int(v), lane));
}

// ---- Kernel 1 (grid 512 = 2 blocks/CU, no tail):
//      blocks 0..255 Gram; 256..511 colsum partials; 256..271 ALSO t1 slice ----
__global__ __launch_bounds__(512) void k_gram_colsum(const float* __restrict__ qt,
                                                     const float* __restrict__ x,
                                                     const float* __restrict__ wv,
                                                     float* __restrict__ ws){
    int lane = threadIdx.x & 63, wid = threadIdx.x >> 6;
    if (blockIdx.x == 0 && threadIdx.x == 0)
        __hip_atomic_store((unsigned*)(ws + WS_CTR), 0u, __ATOMIC_RELEASE, __HIP_MEMORY_SCOPE_AGENT);
    if (blockIdx.x < 256){
        float* G = ws + WS_G;
        int gw = blockIdx.x * 8 + wid;          // 0..2047 waves
        int i = gw >> 4, jb = gw & 15;
        float qi[8];
#pragma unroll
        for (int s = 0; s < 8; ++s){ int idx = lane + 64*s; qi[s] = (idx < NDIM) ? qt[i*NDIM + idx] : 0.f; }
#pragma unroll
        for (int t = 0; t < 8; ++t){
            int j = jb + 16*t;
            float acc = 0.f;
#pragma unroll
            for (int s = 0; s < 8; ++s){
                int idx = lane + 64*s;
                float qj = (idx < NDIM) ? qt[j*NDIM + idx] : 0.f;
                acc = fmaf(qi[s], qj, acc);
            }
#pragma unroll
            for (int d = 1; d < 64; d <<= 1) acc += __shfl_xor(acc, d);
            if (lane == 0) G[i*MD + j] = acc;
        }
    } else {
        int cb = blockIdx.x - 256;              // 0..255, rows cb*64..+64
        int col = threadIdx.x;
        if (col < NDIM){
            const float* xp = x + (size_t)cb*64*NDIM + col;
            float acc = 0.f;
#pragma unroll 4
            for (int r = 0; r < 64; ++r) acc += xp[(size_t)r*NDIM];
            ws[WS_PART + cb*NDIM + col] = acc;
        }
        if (cb < 16){
            int m = cb*8 + wid;                 // t1 slice: one row per wave
            float acc = 0.f;
#pragma unroll
            for (int s = 0; s < 8; ++s){
                int idx = lane + 64*s;
                if (idx < NDIM) acc = fmaf(qt[m*NDIM + idx], wv[idx], acc);
            }
#pragma unroll
            for (int d = 1; d < 64; d <<= 1) acc += __shfl_xor(acc, d);
            if (lane == 0) ws[WS_T1 + m] = acc;
        }
    }
}

// ---- Kernel 2 (grid 236 = 1 block/CU): CG (2 cols, 2 barriers/iter) + fused R/RW;
//      blocks 0..58 ALSO: xbar slice -> release -> poll all 59 -> W2 rows (8/block, wide) ----
#define G_LD(n) float4 t##n = *(const float4*)(Gp + 4*(n)); \
                float Ga##n = t##n.x, Gb##n = t##n.y, Gc##n = t##n.z, Gd##n = t##n.w;
#define G_DOT(n) pa = fmaf(Ga##n, rdl(rch.x, 2*(n)),   pa); \
                 pb = fmaf(Gb##n, rdl(rch.y, 2*(n)),   pb); \
                 pa = fmaf(Gc##n, rdl(rch.x, 2*(n)+1), pa); \
                 pb = fmaf(Gd##n, rdl(rch.y, 2*(n)+1), pb);

__global__ __launch_bounds__(256, 1) void k_cg_xbar(const float* __restrict__ qt,
                                                    const float* __restrict__ alpha,
                                                    const float* __restrict__ lw,
                                                    const float* __restrict__ lb,
                                                    float* __restrict__ ws){
    int tid = threadIdx.x, lane = tid & 63, wid = tid >> 6;
    __shared__ __align__(16) float rl[2][2][128];    // [buf][c][row] — double-buffered r
    __shared__ float part[2][2][128];                // [seg][c][row] partial dots
    {
        int row = tid & 127, seg = tid >> 7;             // seg in {0,1}
        int c   = seg;
        int col = blockIdx.x*2 + c;                      // 0..471 (col 471 = t1 RHS)
        const float* Gp = ws + WS_G + row*MD + seg*64;   // 64 named scalars (true VGPRs)
        G_LD(0) G_LD(1) G_LD(2)  G_LD(3)  G_LD(4)  G_LD(5)  G_LD(6)  G_LD(7)
        G_LD(8) G_LD(9) G_LD(10) G_LD(11) G_LD(12) G_LD(13) G_LD(14) G_LD(15)
        float bvv = (col < NDIM) ? qt[row*NDIM + col] : ws[WS_T1 + row];
        float xv = 0.f, rv = bvv, pv = 0.f, sv = 0.f, gam = 1.f, alf = 1.f;
        int buf = 0;
        rl[0][c][row] = rv;
        for (int it = 0; it < CGIT; ++it){
            __syncthreads();                             // A: rl[buf] visible; part free
#pragma unroll
            for (int cc = 0; cc < 2; ++cc){
                float2 rch = *(const float2*)&rl[buf][cc][seg*64 + 2*(lane & 31)];
                float pa = 0.f, pb = 0.f;
                G_DOT(0) G_DOT(1) G_DOT(2)  G_DOT(3)  G_DOT(4)  G_DOT(5)  G_DOT(6)  G_DOT(7)
                G_DOT(8) G_DOT(9) G_DOT(10) G_DOT(11) G_DOT(12) G_DOT(13) G_DOT(14) G_DOT(15)
                part[seg][cc][row] = pa + pb;
            }
            __syncthreads();                             // B: part visible; rl[buf] reads done
            float y = part[0][c][row] + part[1][c][row];
            // dots redundant per wave (no 3rd barrier): rows lane & lane+64 of col c
            float r0 = rl[buf][c][lane],      r1 = rl[buf][c][lane + 64];
            float y0 = part[0][c][lane]      + part[1][c][lane];
            float y1 = part[0][c][lane + 64] + part[1][c][lane + 64];
            float t0 = fmaf(r0, r0, r1*r1);
            float t1 = fmaf(y0, r0, y1*r1);
#pragma unroll
            for (int d = 1; d < 64; d <<= 1){ t0 += __shfl_xor(t0, d); t1 += __shfl_xor(t1, d); }
            float gp = t0, dl = t1;                      // gamma'=(r,r), delta=(Gr,r)
            float bet, anew;
            if (it == 0){ bet = 0.f; anew = gp / fmaxf(dl, 1e-30f); }
            else { bet = gp / fmaxf(gam, 1e-30f); anew = gp / fmaxf(dl - bet*gp/alf, 1e-30f); }
            pv = fmaf(bet, pv, rv);
            sv = fmaf(bet, sv, y);
            xv = fmaf(anew, pv, xv);
            rv = fmaf(-anew, sv, rv);
            gam = gp; alf = anew;
            rl[buf^1][c][row] = rv;                      // write other buffer: no WAR race
            buf ^= 1;
        }
        // ---- fused epilogue: R rows 2b,2b+1 (or RW for col 471) ----
        rl[buf][c][row] = xv;                            // own slot; readers are on rl[buf^1]
        __syncthreads();
        float sc = alpha[0] / (float)NDIM;
        float2 wc0 = ((const float2*)&rl[buf][0][0])[lane];
        float2 wc1 = ((const float2*)&rl[buf][1][0])[lane];
        int i0 = tid;
        int i1 = (tid + 256 < NDIM) ? tid + 256 : (NDIM - 1);   // clamp (guarded store)
        float a0=0.f, a1=0.f, b0=0.f, b1=0.f;
#pragma unroll
        for (int l = 0; l < 64; ++l){
            float w0a = rdl(wc0.x, l), w0b = rdl(wc0.y, l);
            float w1a = rdl(wc1.x, l), w1b = rdl(wc1.y, l);
            float qa0 = qt[(2*l+0)*NDIM + i0], qa1 = qt[(2*l+0)*NDIM + i1];
            float qb0 = qt[(2*l+1)*NDIM + i0], qb1 = qt[(2*l+1)*NDIM + i1];
            a0 = fmaf(qa0, w0a, a0); a0 = fmaf(qb0, w0b, a0);
            a1 = fmaf(qa1, w0a, a1); a1 = fmaf(qb1, w0b, a1);
            b0 = fmaf(qa0, w1a, b0); b0 = fmaf(qb0, w1b, b0);
            b1 = fmaf(qa1, w1a, b1); b1 = fmaf(qb1, w1b, b1);
        }
        int col0 = blockIdx.x*2, col1 = col0 + 1;
        ws[WS_R + (size_t)col0*NDIM + i0] = sc*a0;
        if (tid + 256 < NDIM) ws[WS_R + (size_t)col0*NDIM + tid+256] = sc*a1;
        if (col1 < NDIM){
            ws[WS_R + (size_t)col1*NDIM + i0] = sc*b0;
            if (tid + 256 < NDIM) ws[WS_R + (size_t)col1*NDIM + tid+256] = sc*b1;
        } else {
            ws[WS_RW + i0] = sc*b0;
            if (tid + 256 < NDIM) ws[WS_RW + tid+256] = sc*b1;
        }
    }
    // ---- xbar + W2 tail on blocks 0..58 (all 59 finish CG ~simultaneously: short wait;
    //      W2 stays 59-wide — R18 lesson: prologue work wants width) ----
    if (blockIdx.x < 59){
        __shared__ float p2[4][8];
        unsigned* ctr = (unsigned*)(ws + WS_CTR);
        __syncthreads();                        // retire epilogue LDS use before reuse
        int b2 = blockIdx.x;
        int cl = tid & 7, seg2 = tid >> 3;      // seg2 0..31
        int col = b2*8 + cl;
        float acc = 0.f;
        if (col < NDIM){
#pragma unroll
            for (int q = 0; q < 8; ++q) acc += ws[WS_PART + (seg2*8 + q)*NDIM + col];
        }
        acc += __shfl_xor(acc, 8);
        acc += __shfl_xor(acc, 16);
        acc += __shfl_xor(acc, 32);
        if (lane < 8) p2[wid][lane] = acc;
        __syncthreads();
        if (tid < 8){
            float t = ((p2[0][tid] + p2[1][tid]) + (p2[2][tid] + p2[3][tid]));
            int c2 = b2*8 + tid;
            if (c2 < NDIM) ws[WS_XBAR + c2] = t * (1.0f / TD);
        }
        __syncthreads();
        if (tid == 0){                          // RELEASE publishes this block's xbar slice
            __hip_atomic_fetch_add(ctr, 1u, __ATOMIC_RELEASE, __HIP_MEMORY_SCOPE_AGENT);
            while (__hip_atomic_load(ctr, __ATOMIC_RELAXED, __HIP_MEMORY_SCOPE_AGENT) < 59u)
                __builtin_amdgcn_s_sleep(2);    // RELAXED poll (R15: no ACQUIRE in loop)
            __builtin_amdgcn_fence(__ATOMIC_ACQUIRE, "agent");
        }
        __syncthreads();
        // W2 rows i = b2*8 + r, r = 0..7 (4 waves -> 2 rounds)
        for (int r = wid; r < 8; r += 4){
            int i = b2*8 + r;
            if (i < NDIM){
                float acc2 = 0.f;
#pragma unroll
                for (int s = 0; s < 8; ++s){
                    int idx = lane + 64*s;
                    if (idx < NDIM) acc2 = fmaf(lw[(size_t)i*NDIM + idx], ws[WS_XBAR + idx], acc2);
                }
#pragma unroll
                for (int d = 1; d < 64; d <<= 1) acc2 += __shfl_xor(acc2, d);
                if (lane == 0) ws[WS_W2 + i] = acc2 + lb[i];
            }
        }
    }
}

// ---- Kernel 3: pure single-block solver (no atomics, no spin; boundary guarantees W2/R) ----
__global__ __launch_bounds__(512, 2) void k_iter(const float* __restrict__ wv,
                                              const float* __restrict__ alpha, const float* __restrict__ lamda,
                                              const float* __restrict__ rho_p, const float* __restrict__ mu_p,
                                              const float* __restrict__ ws, float* __restrict__ out){
    int tid = threadIdx.x, lane = tid & 63, wid = tid >> 6;
    bool act = tid < NDIM;
    int ti = act ? tid : 0;
    float rho = rho_p[0], mu = mu_p[0], lam = lamda[0];
    float sc  = alpha[0] / (float)NDIM;
    float wi  = act ? wv[tid]         : 0.f;
    float Rwi = act ? ws[WS_RW + tid] : 0.f;
    float W2i = act ? ws[WS_W2 + tid] : 0.f;

    __shared__ __align__(16) unsigned bins[1024];   // 4 buffers x 256 bins
    __shared__ __align__(8) float2 spair[64];
    __shared__ float warr[8];
    __shared__ unsigned wcnt[8];

    bins[tid] = 0u; bins[tid + 512] = 0u;
    __syncthreads();

    float z = 0.f, u = 0.f, Ruv = 0.f, Rzv = 0.f, Sz = 0.f;
    unsigned tau = 0xFFFFFFFFu;                     // warm-start threshold (iter 0: forces full select)
    for (int it = 0; it < 10; ++it){
        float Rv = Ruv - rho*(Rzv - Rwi);
        float b  = wi + Rv;
        float grad = W2i + rho*(z - b) + u + 2.f*lam*(Sz - 1.f);
        float zn = z - mu*grad;
        zn = (act && zn > 0.f) ? zn : 0.f;
        unsigned bits = __float_as_uint(zn);

        // ---- warm-tau fast path with SPECULATIVE Sz reduce (one barrier) ----
        bool cge = act && (bits >= tau);
        unsigned long long cm = __ballot(cge);
        float vs = cge ? zn : 0.f;
#pragma unroll
        for (int d = 1; d < 64; d <<= 1) vs += __shfl_xor(vs, d);
        if (lane == 0){ wcnt[wid] = (unsigned)__popcll(cm); warr[wid] = vs; }
        __syncthreads();
        int cnt0 = 0;
#pragma unroll
        for (int w2 = 0; w2 < 8; ++w2) cnt0 += (int)wcnt[w2];
        bool fast = (cnt0 == KSEL);
        unsigned prefix = tau;
        unsigned long long mb;

        if (fast){
            z = cge ? zn : 0.f;                         // tau>0 in fast path => cge == (z>0)
            mb = cm;                                    // warr/wcnt already correct
        } else {
            // full radix select with early exit (bins pre-zeroed)
            prefix = 0; unsigned need = KSEL;
#pragma unroll
            for (int pass = 3; pass >= 0; --pass){
                int sh = pass*8;
                unsigned* bp = bins + ((3 - pass) << 8);
                bool av = (pass == 3) || ((bits >> (sh + 8)) == (prefix >> (sh + 8)));
                if (av) atomicAdd(&bp[(bits >> sh) & 255u], 1u);
                __syncthreads();
                int base = 255 - 4*lane;
                uint4 bq = *(const uint4*)&bp[base - 3];
                unsigned b3 = bq.x, b2 = bq.y, b1 = bq.z, b0 = bq.w;
                unsigned csum = b0 + b1 + b2 + b3;
                unsigned incl = csum;
#pragma unroll
                for (int d = 1; d < 64; d <<= 1){ unsigned t = __shfl_up(incl, d); if (lane >= d) incl += t; }
                unsigned excl = incl - csum;
                bool hit = (excl < need) && (need <= incl);
                unsigned long long hm = __ballot(hit);
                int hl = __ffsll((long long)hm) - 1;
                unsigned c0 = excl + b0, c1 = c0 + b1, c2 = c1 + b2;
                int byte; unsigned above, cntc;
                if      (need <= c0){ byte = base;   above = excl; cntc = b0; }
                else if (need <= c1){ byte = base-1; above = c0;   cntc = b1; }
                else if (need <= c2){ byte = base-2; above = c1;   cntc = b2; }
                else                { byte = base-3; above = c2;   cntc = b3; }
                byte  = __shfl(byte, hl);
                above = (unsigned)__shfl((int)above, hl);
                cntc  = (unsigned)__shfl((int)cntc, hl);
                prefix |= ((unsigned)byte) << sh;
                need -= above;
                if (cntc == need) break;
            }
            tau = prefix;
            z = (act && bits >= prefix) ? zn : 0.f;
            bool flag = z > 0.f;
            mb = __ballot(flag);
            float v = z;
#pragma unroll
            for (int d = 1; d < 64; d <<= 1) v += __shfl_xor(v, d);
            if (lane == 0){ warr[wid] = v; wcnt[wid] = (unsigned)__popcll(mb); }
            __syncthreads();
        }
        Sz = ((warr[0]+warr[1])+(warr[2]+warr[3])) + ((warr[4]+warr[5])+(warr[6]+warr[7]));

        if (it < 9){
            bool flag = z > 0.f;
            unsigned off = 0;
#pragma unroll
            for (int w2 = 0; w2 < 8; ++w2) if (w2 < wid) off += wcnt[w2];
            off += (unsigned)__popcll(mb & ((1ull << lane) - 1ull));
            int cnt = 0;
#pragma unroll
            for (int w2 = 0; w2 < 8; ++w2) cnt += (int)wcnt[w2];
            if (flag){ spair[off] = make_float2(__int_as_float(tid), z); }
            if (tid >= cnt && tid < 64){ spair[tid] = make_float2(__int_as_float(0), 0.f); }
            bins[tid] = 0u; bins[tid + 512] = 0u;
            __syncthreads();

            float2 pp = spair[lane];
            const float* Rb = ws + WS_R;
            float rvv[56];
#pragma unroll
            for (int s = 0; s < 56; ++s){
                int j = __float_as_int(rdl(pp.x, s));
                rvv[s] = Rb[(size_t)j*NDIM + ti];
            }
            float a0=0.f, a1=0.f, a2=0.f, a3=0.f;
#pragma unroll
            for (int s = 0; s < 56; s += 4){
                a0 = fmaf(rvv[s+0], rdl(pp.y, s+0), a0);
                a1 = fmaf(rvv[s+1], rdl(pp.y, s+1), a1);
                a2 = fmaf(rvv[s+2], rdl(pp.y, s+2), a2);
                a3 = fmaf(rvv[s+3], rdl(pp.y, s+3), a3);
            }
            float acc = (a0+a1) + (a2+a3);
            float Rbv = Rwi + sc*Rv;                // R@b = Rw + (alpha/N)*Rv   (P^2 = P)
            u   += rho*(z - b);
            Ruv += rho*(acc - Rbv);
            Rzv  = acc;
        }
    }
    if (act) out[tid] = z / (Sz + 1e-8f);
}

extern "C" void kernel_launch(void* const* d_in, const int* in_sizes, int n_in,
                              void* d_out, int out_size, void* d_ws, size_t ws_size,
                              hipStream_t stream) {
    const float* x     = (const float*)d_in[0];
    const float* qt    = (const float*)d_in[1];
    const float* wv    = (const float*)d_in[2];
    // d_in[3] = b1 (unused by forward math)
    const float* alpha = (const float*)d_in[4];
    const float* lamda = (const float*)d_in[5];
    const float* rho   = (const float*)d_in[6];
    const float* mu    = (const float*)d_in[7];
    const float* lw    = (const float*)d_in[8];
    const float* lb    = (const float*)d_in[9];
    float* out = (float*)d_out;
    float* ws  = (float*)d_ws;

    k_gram_colsum<<<512, 512, 0, stream>>>(qt, x, wv, ws);
    k_cg_xbar    <<<236, 256, 0, stream>>>(qt, alpha, lw, lb, ws);
    k_iter       <<<1,   512, 0, stream>>>(wv, alpha, lamda, rho, mu, ws, out);
}

// Round 20
// 52.386 us; speedup vs baseline: 1.1872x; 1.0476x over previous
//
#include <hip/hip_runtime.h>

// Problem constants
#define NDIM 471
#define MD   128
#define TD   16384
#define KSEL 50
#define CGIT 3

// ws float-offset layout
#define WS_PART   0                 // [256][471] column-sum partials
#define WS_G      120832            // [128][128] Gram
#define WS_T1     137216            // [128]  t1 = Q w
#define WS_XBAR   197888            // [471]
#define WS_W2     198400            // [471]
#define WS_RW     198912            // [471]  Rw = R @ w
#define WS_CTR    199384            // [1]    xbar-done counter (zeroed by k1 each call)
#define WS_R      199424            // [471][471] R = (alpha/N) Q^T Ginv Q (row col = R[col][:], symmetric)

// SGPR broadcast: readlane with compile-time lane index -> v_readlane_b32 s,v,imm
static __device__ __forceinline__ float rdl(float v, int lane){
    return __int_as_float(__builtin_amdgcn_readlane(__float_as_int(v), lane));
}

// ---- Kernel 1 (grid 512 = 2 blocks/CU, no tail):
//      blocks 0..255 Gram; 256..511 colsum partials; 256..271 ALSO t1 slice ----
__global__ __launch_bounds__(512) void k_gram_colsum(const float* __restrict__ qt,
                                                     const float* __restrict__ x,
                                                     const float* __restrict__ wv,
                                                     float* __restrict__ ws){
    int lane = threadIdx.x & 63, wid = threadIdx.x >> 6;
    if (blockIdx.x == 0 && threadIdx.x == 0)
        __hip_atomic_store((unsigned*)(ws + WS_CTR), 0u, __ATOMIC_RELEASE, __HIP_MEMORY_SCOPE_AGENT);
    if (blockIdx.x < 256){
        float* G = ws + WS_G;
        int gw = blockIdx.x * 8 + wid;          // 0..2047 waves
        int i = gw >> 4, jb = gw & 15;
        float qi[8];
#pragma unroll
        for (int s = 0; s < 8; ++s){ int idx = lane + 64*s; qi[s] = (idx < NDIM) ? qt[i*NDIM + idx] : 0.f; }
#pragma unroll
        for (int t = 0; t < 8; ++t){
            int j = jb + 16*t;
            float acc = 0.f;
#pragma unroll
            for (int s = 0; s < 8; ++s){
                int idx = lane + 64*s;
                float qj = (idx < NDIM) ? qt[j*NDIM + idx] : 0.f;
                acc = fmaf(qi[s], qj, acc);
            }
#pragma unroll
            for (int d = 1; d < 64; d <<= 1) acc += __shfl_xor(acc, d);
            if (lane == 0) G[i*MD + j] = acc;
        }
    } else {
        int cb = blockIdx.x - 256;              // 0..255, rows cb*64..+64
        int col = threadIdx.x;
        if (col < NDIM){
            // R19 lesson candidate: unroll 4 -> only ~4 outstanding loads/thread
            // (latency-bound ~2 TB/s). Full unroll + 4 chains -> BW-bound.
            const float* xp = x + (size_t)cb*64*NDIM + col;
            float a0=0.f, a1=0.f, a2=0.f, a3=0.f;
#pragma unroll
            for (int r = 0; r < 64; r += 4){
                a0 += xp[(size_t)(r+0)*NDIM];
                a1 += xp[(size_t)(r+1)*NDIM];
                a2 += xp[(size_t)(r+2)*NDIM];
                a3 += xp[(size_t)(r+3)*NDIM];
            }
            ws[WS_PART + cb*NDIM + col] = (a0+a1) + (a2+a3);
        }
        if (cb < 16){
            int m = cb*8 + wid;                 // t1 slice: one row per wave
            float acc = 0.f;
#pragma unroll
            for (int s = 0; s < 8; ++s){
                int idx = lane + 64*s;
                if (idx < NDIM) acc = fmaf(qt[m*NDIM + idx], wv[idx], acc);
            }
#pragma unroll
            for (int d = 1; d < 64; d <<= 1) acc += __shfl_xor(acc, d);
            if (lane == 0) ws[WS_T1 + m] = acc;
        }
    }
}

// ---- Kernel 2 (grid 236 = 1 block/CU): CG (2 cols, 2 barriers/iter) + fused R/RW;
//      blocks 0..58 ALSO: xbar slice -> release -> poll all 59 -> W2 rows (8/block, wide) ----
#define G_LD(n) float4 t##n = *(const float4*)(Gp + 4*(n)); \
                float Ga##n = t##n.x, Gb##n = t##n.y, Gc##n = t##n.z, Gd##n = t##n.w;
#define G_DOT(n) pa = fmaf(Ga##n, rdl(rch.x, 2*(n)),   pa); \
                 pb = fmaf(Gb##n, rdl(rch.y, 2*(n)),   pb); \
                 pa = fmaf(Gc##n, rdl(rch.x, 2*(n)+1), pa); \
                 pb = fmaf(Gd##n, rdl(rch.y, 2*(n)+1), pb);

__global__ __launch_bounds__(256, 1) void k_cg_xbar(const float* __restrict__ qt,
                                                    const float* __restrict__ alpha,
                                                    const float* __restrict__ lw,
                                                    const float* __restrict__ lb,
                                                    float* __restrict__ ws){
    int tid = threadIdx.x, lane = tid & 63, wid = tid >> 6;
    __shared__ __align__(16) float rl[2][2][128];    // [buf][c][row] — double-buffered r
    __shared__ float part[2][2][128];                // [seg][c][row] partial dots
    {
        int row = tid & 127, seg = tid >> 7;             // seg in {0,1}
        int c   = seg;
        int col = blockIdx.x*2 + c;                      // 0..471 (col 471 = t1 RHS)
        const float* Gp = ws + WS_G + row*MD + seg*64;   // 64 named scalars (true VGPRs)
        G_LD(0) G_LD(1) G_LD(2)  G_LD(3)  G_LD(4)  G_LD(5)  G_LD(6)  G_LD(7)
        G_LD(8) G_LD(9) G_LD(10) G_LD(11) G_LD(12) G_LD(13) G_LD(14) G_LD(15)
        float bvv = (col < NDIM) ? qt[row*NDIM + col] : ws[WS_T1 + row];
        float xv = 0.f, rv = bvv, pv = 0.f, sv = 0.f, gam = 1.f, alf = 1.f;
        int buf = 0;
        rl[0][c][row] = rv;
        for (int it = 0; it < CGIT; ++it){
            __syncthreads();                             // A: rl[buf] visible; part free
#pragma unroll
            for (int cc = 0; cc < 2; ++cc){
                float2 rch = *(const float2*)&rl[buf][cc][seg*64 + 2*(lane & 31)];
                float pa = 0.f, pb = 0.f;
                G_DOT(0) G_DOT(1) G_DOT(2)  G_DOT(3)  G_DOT(4)  G_DOT(5)  G_DOT(6)  G_DOT(7)
                G_DOT(8) G_DOT(9) G_DOT(10) G_DOT(11) G_DOT(12) G_DOT(13) G_DOT(14) G_DOT(15)
                part[seg][cc][row] = pa + pb;
            }
            __syncthreads();                             // B: part visible; rl[buf] reads done
            float y = part[0][c][row] + part[1][c][row];
            // dots redundant per wave (no 3rd barrier): rows lane & lane+64 of col c
            float r0 = rl[buf][c][lane],      r1 = rl[buf][c][lane + 64];
            float y0 = part[0][c][lane]      + part[1][c][lane];
            float y1 = part[0][c][lane + 64] + part[1][c][lane + 64];
            float t0 = fmaf(r0, r0, r1*r1);
            float t1 = fmaf(y0, r0, y1*r1);
#pragma unroll
            for (int d = 1; d < 64; d <<= 1){ t0 += __shfl_xor(t0, d); t1 += __shfl_xor(t1, d); }
            float gp = t0, dl = t1;                      // gamma'=(r,r), delta=(Gr,r)
            float bet, anew;
            if (it == 0){ bet = 0.f; anew = gp / fmaxf(dl, 1e-30f); }
            else { bet = gp / fmaxf(gam, 1e-30f); anew = gp / fmaxf(dl - bet*gp/alf, 1e-30f); }
            pv = fmaf(bet, pv, rv);
            sv = fmaf(bet, sv, y);
            xv = fmaf(anew, pv, xv);
            rv = fmaf(-anew, sv, rv);
            gam = gp; alf = anew;
            rl[buf^1][c][row] = rv;                      // write other buffer: no WAR race
            buf ^= 1;
        }
        // ---- fused epilogue: R rows 2b,2b+1 (or RW for col 471) ----
        rl[buf][c][row] = xv;                            // own slot; readers are on rl[buf^1]
        __syncthreads();
        float sc = alpha[0] / (float)NDIM;
        float2 wc0 = ((const float2*)&rl[buf][0][0])[lane];
        float2 wc1 = ((const float2*)&rl[buf][1][0])[lane];
        int i0 = tid;
        int i1 = (tid + 256 < NDIM) ? tid + 256 : (NDIM - 1);   // clamp (guarded store)
        float a0=0.f, a1=0.f, b0=0.f, b1=0.f;
#pragma unroll
        for (int l = 0; l < 64; ++l){
            float w0a = rdl(wc0.x, l), w0b = rdl(wc0.y, l);
            float w1a = rdl(wc1.x, l), w1b = rdl(wc1.y, l);
            float qa0 = qt[(2*l+0)*NDIM + i0], qa1 = qt[(2*l+0)*NDIM + i1];
            float qb0 = qt[(2*l+1)*NDIM + i0], qb1 = qt[(2*l+1)*NDIM + i1];
            a0 = fmaf(qa0, w0a, a0); a0 = fmaf(qb0, w0b, a0);
            a1 = fmaf(qa1, w0a, a1); a1 = fmaf(qb1, w0b, a1);
            b0 = fmaf(qa0, w1a, b0); b0 = fmaf(qb0, w1b, b0);
            b1 = fmaf(qa1, w1a, b1); b1 = fmaf(qb1, w1b, b1);
        }
        int col0 = blockIdx.x*2, col1 = col0 + 1;
        ws[WS_R + (size_t)col0*NDIM + i0] = sc*a0;
        if (tid + 256 < NDIM) ws[WS_R + (size_t)col0*NDIM + tid+256] = sc*a1;
        if (col1 < NDIM){
            ws[WS_R + (size_t)col1*NDIM + i0] = sc*b0;
            if (tid + 256 < NDIM) ws[WS_R + (size_t)col1*NDIM + tid+256] = sc*b1;
        } else {
            ws[WS_RW + i0] = sc*b0;
            if (tid + 256 < NDIM) ws[WS_RW + tid+256] = sc*b1;
        }
    }
    // ---- xbar + W2 tail on blocks 0..58 (59 blocks finish CG ~simultaneously) ----
    if (blockIdx.x < 59){
        __shared__ float p2[4][8];
        unsigned* ctr = (unsigned*)(ws + WS_CTR);
        __syncthreads();                        // retire epilogue LDS use before reuse
        int b2 = blockIdx.x;
        int cl = tid & 7, seg2 = tid >> 3;      // seg2 0..31
        int col = b2*8 + cl;
        float acc = 0.f;
        if (col < NDIM){
#pragma unroll
            for (int q = 0; q < 8; ++q) acc += ws[WS_PART + (seg2*8 + q)*NDIM + col];
        }
        acc += __shfl_xor(acc, 8);
        acc += __shfl_xor(acc, 16);
        acc += __shfl_xor(acc, 32);
        if (lane < 8) p2[wid][lane] = acc;
        __syncthreads();
        if (tid < 8){
            float t = ((p2[0][tid] + p2[1][tid]) + (p2[2][tid] + p2[3][tid]));
            int c2 = b2*8 + tid;
            if (c2 < NDIM) ws[WS_XBAR + c2] = t * (1.0f / TD);
        }
        __syncthreads();
        if (tid == 0){                          // RELEASE publishes this block's xbar slice
            __hip_atomic_fetch_add(ctr, 1u, __ATOMIC_RELEASE, __HIP_MEMORY_SCOPE_AGENT);
            while (__hip_atomic_load(ctr, __ATOMIC_RELAXED, __HIP_MEMORY_SCOPE_AGENT) < 59u)
                __builtin_amdgcn_s_sleep(2);    // RELAXED poll (R15: no ACQUIRE in loop)
            __builtin_amdgcn_fence(__ATOMIC_ACQUIRE, "agent");
        }
        __syncthreads();
        // W2 rows i = b2*8 + r, r = 0..7 (4 waves -> 2 rounds; stays 59-wide per R18 lesson)
        for (int r = wid; r < 8; r += 4){
            int i = b2*8 + r;
            if (i < NDIM){
                float acc2 = 0.f;
#pragma unroll
                for (int s = 0; s < 8; ++s){
                    int idx = lane + 64*s;
                    if (idx < NDIM) acc2 = fmaf(lw[(size_t)i*NDIM + idx], ws[WS_XBAR + idx], acc2);
                }
#pragma unroll
                for (int d = 1; d < 64; d <<= 1) acc2 += __shfl_xor(acc2, d);
                if (lane == 0) ws[WS_W2 + i] = acc2 + lb[i];
            }
        }
    }
}

// ---- Kernel 3: pure single-block solver (no atomics, no spin; boundary guarantees W2/R) ----
__global__ __launch_bounds__(512, 2) void k_iter(const float* __restrict__ wv,
                                              const float* __restrict__ alpha, const float* __restrict__ lamda,
                                              const float* __restrict__ rho_p, const float* __restrict__ mu_p,
                                              const float* __restrict__ ws, float* __restrict__ out){
    int tid = threadIdx.x, lane = tid & 63, wid = tid >> 6;
    bool act = tid < NDIM;
    int ti = act ? tid : 0;
    float rho = rho_p[0], mu = mu_p[0], lam = lamda[0];
    float sc  = alpha[0] / (float)NDIM;
    float wi  = act ? wv[tid]         : 0.f;
    float Rwi = act ? ws[WS_RW + tid] : 0.f;
    float W2i = act ? ws[WS_W2 + tid] : 0.f;

    __shared__ __align__(16) unsigned bins[1024];   // 4 buffers x 256 bins
    __shared__ __align__(8) float2 spair[64];
    __shared__ float warr[8];
    __shared__ unsigned wcnt[8];

    bins[tid] = 0u; bins[tid + 512] = 0u;
    __syncthreads();

    float z = 0.f, u = 0.f, Ruv = 0.f, Rzv = 0.f, Sz = 0.f;
    unsigned tau = 0xFFFFFFFFu;                     // warm-start threshold (iter 0: forces full select)
    for (int it = 0; it < 10; ++it){
        float Rv = Ruv - rho*(Rzv - Rwi);
        float b  = wi + Rv;
        float grad = W2i + rho*(z - b) + u + 2.f*lam*(Sz - 1.f);
        float zn = z - mu*grad;
        zn = (act && zn > 0.f) ? zn : 0.f;
        unsigned bits = __float_as_uint(zn);

        // ---- warm-tau fast path with SPECULATIVE Sz reduce (one barrier) ----
        bool cge = act && (bits >= tau);
        unsigned long long cm = __ballot(cge);
        float vs = cge ? zn : 0.f;
#pragma unroll
        for (int d = 1; d < 64; d <<= 1) vs += __shfl_xor(vs, d);
        if (lane == 0){ wcnt[wid] = (unsigned)__popcll(cm); warr[wid] = vs; }
        __syncthreads();
        int cnt0 = 0;
#pragma unroll
        for (int w2 = 0; w2 < 8; ++w2) cnt0 += (int)wcnt[w2];
        bool fast = (cnt0 == KSEL);
        unsigned prefix = tau;
        unsigned long long mb;

        if (fast){
            z = cge ? zn : 0.f;                         // tau>0 in fast path => cge == (z>0)
            mb = cm;                                    // warr/wcnt already correct
        } else {
            // full radix select with early exit (bins pre-zeroed)
            prefix = 0; unsigned need = KSEL;
#pragma unroll
            for (int pass = 3; pass >= 0; --pass){
                int sh = pass*8;
                unsigned* bp = bins + ((3 - pass) << 8);
                bool av = (pass == 3) || ((bits >> (sh + 8)) == (prefix >> (sh + 8)));
                if (av) atomicAdd(&bp[(bits >> sh) & 255u], 1u);
                __syncthreads();
                int base = 255 - 4*lane;
                uint4 bq = *(const uint4*)&bp[base - 3];
                unsigned b3 = bq.x, b2 = bq.y, b1 = bq.z, b0 = bq.w;
                unsigned csum = b0 + b1 + b2 + b3;
                unsigned incl = csum;
#pragma unroll
                for (int d = 1; d < 64; d <<= 1){ unsigned t = __shfl_up(incl, d); if (lane >= d) incl += t; }
                unsigned excl = incl - csum;
                bool hit = (excl < need) && (need <= incl);
                unsigned long long hm = __ballot(hit);
                int hl = __ffsll((long long)hm) - 1;
                unsigned c0 = excl + b0, c1 = c0 + b1, c2 = c1 + b2;
                int byte; unsigned above, cntc;
                if      (need <= c0){ byte = base;   above = excl; cntc = b0; }
                else if (need <= c1){ byte = base-1; above = c0;   cntc = b1; }
                else if (need <= c2){ byte = base-2; above = c1;   cntc = b2; }
                else                { byte = base-3; above = c2;   cntc = b3; }
                byte  = __shfl(byte, hl);
                above = (unsigned)__shfl((int)above, hl);
                cntc  = (unsigned)__shfl((int)cntc, hl);
                prefix |= ((unsigned)byte) << sh;
                need -= above;
                if (cntc == need) break;
            }
            tau = prefix;
            z = (act && bits >= prefix) ? zn : 0.f;
            bool flag = z > 0.f;
            mb = __ballot(flag);
            float v = z;
#pragma unroll
            for (int d = 1; d < 64; d <<= 1) v += __shfl_xor(v, d);
            if (lane == 0){ warr[wid] = v; wcnt[wid] = (unsigned)__popcll(mb); }
            __syncthreads();
        }
        Sz = ((warr[0]+warr[1])+(warr[2]+warr[3])) + ((warr[4]+warr[5])+(warr[6]+warr[7]));

        if (it < 9){
            bool flag = z > 0.f;
            unsigned off = 0;
#pragma unroll
            for (int w2 = 0; w2 < 8; ++w2) if (w2 < wid) off += wcnt[w2];
            off += (unsigned)__popcll(mb & ((1ull << lane) - 1ull));
            int cnt = 0;
#pragma unroll
            for (int w2 = 0; w2 < 8; ++w2) cnt += (int)wcnt[w2];
            if (flag){ spair[off] = make_float2(__int_as_float(tid), z); }
            if (tid >= cnt && tid < 64){ spair[tid] = make_float2(__int_as_float(0), 0.f); }
            bins[tid] = 0u; bins[tid + 512] = 0u;
            __syncthreads();

            float2 pp = spair[lane];
            const float* Rb = ws + WS_R;
            float rvv[56];
#pragma unroll
            for (int s = 0; s < 56; ++s){
                int j = __float_as_int(rdl(pp.x, s));
                rvv[s] = Rb[(size_t)j*NDIM + ti];
            }
            float a0=0.f, a1=0.f, a2=0.f, a3=0.f;
#pragma unroll
            for (int s = 0; s < 56; s += 4){
                a0 = fmaf(rvv[s+0], rdl(pp.y, s+0), a0);
                a1 = fmaf(rvv[s+1], rdl(pp.y, s+1), a1);
                a2 = fmaf(rvv[s+2], rdl(pp.y, s+2), a2);
                a3 = fmaf(rvv[s+3], rdl(pp.y, s+3), a3);
            }
            float acc = (a0+a1) + (a2+a3);
            float Rbv = Rwi + sc*Rv;                // R@b = Rw + (alpha/N)*Rv   (P^2 = P)
            u   += rho*(z - b);
            Ruv += rho*(acc - Rbv);
            Rzv  = acc;
        }
    }
    if (act) out[tid] = z / (Sz + 1e-8f);
}

extern "C" void kernel_launch(void* const* d_in, const int* in_sizes, int n_in,
                              void* d_out, int out_size, void* d_ws, size_t ws_size,
                              hipStream_t stream) {
    const float* x     = (const float*)d_in[0];
    const float* qt    = (const float*)d_in[1];
    const float* wv    = (const float*)d_in[2];
    // d_in[3] = b1 (unused by forward math)
    const float* alpha = (const float*)d_in[4];
    const float* lamda = (const float*)d_in[5];
    const float* rho   = (const float*)d_in[6];
    const float* mu    = (const float*)d_in[7];
    const float* lw    = (const float*)d_in[8];
    const float* lb    = (const float*)d_in[9];
    float* out = (float*)d_out;
    float* ws  = (float*)d_ws;

    k_gram_colsum<<<512, 512, 0, stream>>>(qt, x, wv, ws);
    k_cg_xbar    <<<236, 256, 0, stream>>>(qt, alpha, lw, lb, ws);
    k_iter       <<<1,   512, 0, stream>>>(wv, alpha, lamda, rho, mu, ws, out);
}